// Round 4
// baseline (78.731 us; speedup 1.0000x reference)
//
#include <hip/hip_runtime.h>

// QuantumKernelMethod, fully fused: out[i][j] = |tr(Q_i M_j)|
// Q_i = phi phi^dag (phi = V(a_i)|0>), M_j = I - 2P_j,
// P_j = sum_{p=8..15} w_p w_p^dag, w_p = V(b_j)|p> (8 basis sims per y).
// Hermitian pack K=256: S[k][l] = diag | sqrt2*Re (k<l) | sqrt2*Im mirror (k>l);
// dot(S_Q, S_M) = tr(QM) exactly. One block = one 64x64 out tile; everything
// (sims, assembly, MFMA) on-CU via LDS. No workspace, single launch.

#define NA 1024
#define NB 1024
#define RT2 1.41421356237f
#define SW 577      // W row stride (floats); sim offset = y*9+p -> 16 distinct banks
#define SQS 264     // S tile row stride (bf16); 132 dw = 4 mod 32 -> uniform spread
#define LDS_BYTES (16*SW*4*2 + 64*SQS*2*2)   // 73856 + 67584 = 141440 B

typedef __attribute__((ext_vector_type(8))) short bf16x8;
typedef __attribute__((ext_vector_type(4))) float f32x4;

__device__ __forceinline__ unsigned short f2bf(float x) {
    union { float f; unsigned u; } v; v.f = x;
    unsigned r = v.u + 0x7fffu + ((v.u >> 16) & 1u);  // RNE
    return (unsigned short)(r >> 16);
}

__device__ __forceinline__ uint4 pack8(const float* f) {
    uint4 u;
    u.x = (unsigned)f2bf(f[0]) | ((unsigned)f2bf(f[1]) << 16);
    u.y = (unsigned)f2bf(f[2]) | ((unsigned)f2bf(f[3]) << 16);
    u.z = (unsigned)f2bf(f[4]) | ((unsigned)f2bf(f[5]) << 16);
    u.w = (unsigned)f2bf(f[6]) | ((unsigned)f2bf(f[7]) << 16);
    return u;
}

// State: 16 complex amps, flat index = b0*8+b1*4+b2*2+b3 (wire w -> bit 3-w).
// Gates take precomputed (c,s) = (cos(t/2), sin(t/2)).
__device__ __forceinline__ void ry_cs(float* sr, float* si, int w, float c, float s) {
    int st = 8 >> w;
    #pragma unroll
    for (int b = 0; b < 16; ++b) {
        if (b & st) continue;
        int j = b | st;
        float r0 = sr[b], i0 = si[b], r1 = sr[j], i1 = si[j];
        sr[b] = c * r0 - s * r1;  si[b] = c * i0 - s * i1;
        sr[j] = s * r0 + c * r1;  si[j] = s * i0 + c * i1;
    }
}

__device__ __forceinline__ void rx_cs(float* sr, float* si, int w, float c, float s) {
    int st = 8 >> w;
    #pragma unroll
    for (int b = 0; b < 16; ++b) {
        if (b & st) continue;
        int j = b | st;
        float r0 = sr[b], i0 = si[b], r1 = sr[j], i1 = si[j];
        sr[b] = c * r0 + s * i1;  si[b] = c * i0 - s * r1;
        sr[j] = c * r1 + s * i0;  si[j] = c * i1 - s * r0;
    }
}

__device__ __forceinline__ void rz_cs(float* sr, float* si, int w, float c, float s) {
    int st = 8 >> w;
    #pragma unroll
    for (int b = 0; b < 16; ++b) {
        if (b & st) continue;
        int j = b | st;
        float r0 = sr[b], i0 = si[b], r1 = sr[j], i1 = si[j];
        sr[b] = c * r0 + s * i0;  si[b] = c * i0 - s * r0;
        sr[j] = c * r1 - s * i1;  si[j] = c * i1 + s * r1;
    }
}

__device__ __forceinline__ void cnot_gate(float* sr, float* si, int cw, int tw) {
    int cs = 8 >> cw, ts = 8 >> tw;
    #pragma unroll
    for (int b = 0; b < 16; ++b) {
        if ((b & cs) && !(b & ts)) {
            int j = b | ts;
            float tr = sr[b]; sr[b] = sr[j]; sr[j] = tr;
            float ti = si[b]; si[b] = si[j]; si[j] = ti;
        }
    }
}

// vec gates from per-sim sincos; 24 param gates from hoisted pc/ps.
__device__ __forceinline__ void ansatz_cs(float* sr, float* si,
                                          const float* vc, const float* vs,
                                          const float* pc, const float* ps) {
    #pragma unroll
    for (int q = 0; q < 4; ++q) ry_cs(sr, si, q, vc[q], vs[q]);
    #pragma unroll
    for (int l = 0; l < 2; ++l) {
        #pragma unroll
        for (int q = 0; q < 4; ++q) {
            rx_cs(sr, si, q, pc[l*12+q*3+0], ps[l*12+q*3+0]);
            ry_cs(sr, si, q, pc[l*12+q*3+1], ps[l*12+q*3+1]);
            rz_cs(sr, si, q, pc[l*12+q*3+2], ps[l*12+q*3+2]);
        }
        cnot_gate(sr, si, 0, 1);
        cnot_gate(sr, si, 1, 2);
        cnot_gate(sr, si, 2, 3);
        cnot_gate(sr, si, 3, 0);
    }
}

__global__ __launch_bounds__(256) void qkm_fused(
    const float* __restrict__ a, const float* __restrict__ b,
    const float* __restrict__ params, float* __restrict__ out) {
    extern __shared__ char lds[];
    float* Wr = (float*)lds;
    float* Wi = Wr + 16 * SW;
    unsigned short* SQ = (unsigned short*)(Wi + 16 * SW);
    unsigned short* SM = SQ + 64 * SQS;

    int tid = threadIdx.x;
    int blk = blockIdx.x;
    int row_base = (blk >> 4) << 6;   // a-rows   [row_base, +64)
    int col_base = (blk & 15) << 6;   // b-rows   [col_base, +64)

    // Hoist param sincos (same for every sim).
    float pc[24], ps[24];
    #pragma unroll
    for (int j = 0; j < 24; ++j) __sincosf(0.5f * params[j], &ps[j], &pc[j]);

    // --- M sims: 512 sims (y in [0,64), basis p in [0,8) -> state 8+p), 2/thread.
    #pragma unroll
    for (int rep = 0; rep < 2; ++rep) {
        int s = tid + rep * 256;
        int y = s >> 3, p = s & 7;
        float4 bv = ((const float4*)b)[col_base + y];
        float vc[4], vs[4];
        __sincosf(0.5f * bv.x, &vs[0], &vc[0]);
        __sincosf(0.5f * bv.y, &vs[1], &vc[1]);
        __sincosf(0.5f * bv.z, &vs[2], &vc[2]);
        __sincosf(0.5f * bv.w, &vs[3], &vc[3]);
        float sr[16], si[16];
        #pragma unroll
        for (int k = 0; k < 16; ++k) { sr[k] = (k == 8 + p) ? 1.f : 0.f; si[k] = 0.f; }
        ansatz_cs(sr, si, vc, vs, pc, ps);
        int off = y * 9 + p;
        #pragma unroll
        for (int l = 0; l < 16; ++l) { Wr[l * SW + off] = sr[l]; Wi[l * SW + off] = si[l]; }
    }

    // --- Q sims: threads 0..63, one phi each, pack straight into SQ.
    if (tid < 64) {
        float4 av = ((const float4*)a)[row_base + tid];
        float vc[4], vs[4];
        __sincosf(0.5f * av.x, &vs[0], &vc[0]);
        __sincosf(0.5f * av.y, &vs[1], &vc[1]);
        __sincosf(0.5f * av.z, &vs[2], &vc[2]);
        __sincosf(0.5f * av.w, &vs[3], &vc[3]);
        float sr[16], si[16];
        #pragma unroll
        for (int k = 0; k < 16; ++k) { sr[k] = (k == 0) ? 1.f : 0.f; si[k] = 0.f; }
        ansatz_cs(sr, si, vc, vs, pc, ps);
        #pragma unroll
        for (int k = 0; k < 16; ++k) {
            float rk = sr[k], ik = si[k];
            float row[16];
            #pragma unroll
            for (int l = 0; l < 16; ++l) {
                if (l < k)       row[l] = RT2 * (si[l] * rk - sr[l] * ik);
                else if (l == k) row[l] = rk * rk + ik * ik;
                else             row[l] = RT2 * (rk * sr[l] + ik * si[l]);
            }
            *(uint4*)(SQ + tid * SQS + k * 16)     = pack8(row);
            *(uint4*)(SQ + tid * SQS + k * 16 + 8) = pack8(row + 8);
        }
    }
    __syncthreads();

    // --- M assembly: y = tid>>2, t = tid&3; two passes of a row-pair each.
    {
        int y = tid >> 2, t = tid & 3;
        int base = y * 9;
        #pragma unroll
        for (int h = 0; h < 2; ++h) {
            int k0 = 4 * t + 2 * h;
            float re0[16], im0[16], re1[16], im1[16];
            #pragma unroll
            for (int l = 0; l < 16; ++l) { re0[l]=0.f; im0[l]=0.f; re1[l]=0.f; im1[l]=0.f; }
            #pragma unroll
            for (int p2 = 0; p2 < 8; ++p2) {
                float wr0 = Wr[k0 * SW + base + p2],       wi0 = Wi[k0 * SW + base + p2];
                float wr1 = Wr[(k0 + 1) * SW + base + p2], wi1 = Wi[(k0 + 1) * SW + base + p2];
                #pragma unroll
                for (int l = 0; l < 16; ++l) {
                    float wrl = Wr[l * SW + base + p2], wil = Wi[l * SW + base + p2];
                    re0[l] += wr0 * wrl + wi0 * wil;   // Re P_{k0,l}
                    im0[l] += wil * wr0 - wrl * wi0;   // Im P_{l,k0}
                    re1[l] += wr1 * wrl + wi1 * wil;
                    im1[l] += wil * wr1 - wrl * wi1;
                }
            }
            float row[16];
            #pragma unroll
            for (int l = 0; l < 16; ++l) {
                float off = (l < k0) ? im0[l] : re0[l];
                row[l] = (l == k0) ? (1.f - 2.f * re0[l]) : (-2.f * RT2 * off);
            }
            *(uint4*)(SM + y * SQS + k0 * 16)     = pack8(row);
            *(uint4*)(SM + y * SQS + k0 * 16 + 8) = pack8(row + 8);
            int k1 = k0 + 1;
            #pragma unroll
            for (int l = 0; l < 16; ++l) {
                float off = (l < k1) ? im1[l] : re1[l];
                row[l] = (l == k1) ? (1.f - 2.f * re1[l]) : (-2.f * RT2 * off);
            }
            *(uint4*)(SM + y * SQS + k1 * 16)     = pack8(row);
            *(uint4*)(SM + y * SQS + k1 * 16 + 8) = pack8(row + 8);
        }
    }
    __syncthreads();

    // --- MFMA: 4 waves 2x2, each wave 32x32 = 2x2 fragments, K=256 from LDS.
    int wave = tid >> 6, lane = tid & 63;
    int wi = wave >> 1, wj = wave & 1;
    int m16 = lane & 15, quad = lane >> 4;
    const unsigned short* q0 = SQ + (wi * 32 + m16) * SQS + quad * 8;
    const unsigned short* q1 = q0 + 16 * SQS;
    const unsigned short* m0 = SM + (wj * 32 + m16) * SQS + quad * 8;
    const unsigned short* m1 = m0 + 16 * SQS;

    f32x4 a00 = {0.f,0.f,0.f,0.f}, a01 = {0.f,0.f,0.f,0.f};
    f32x4 a10 = {0.f,0.f,0.f,0.f}, a11 = {0.f,0.f,0.f,0.f};
    #pragma unroll
    for (int kk = 0; kk < 8; ++kk) {
        bf16x8 qa = *(const bf16x8*)(q0 + kk * 32);
        bf16x8 qb = *(const bf16x8*)(q1 + kk * 32);
        bf16x8 ma = *(const bf16x8*)(m0 + kk * 32);
        bf16x8 mb = *(const bf16x8*)(m1 + kk * 32);
        a00 = __builtin_amdgcn_mfma_f32_16x16x32_bf16(qa, ma, a00, 0, 0, 0);
        a01 = __builtin_amdgcn_mfma_f32_16x16x32_bf16(qa, mb, a01, 0, 0, 0);
        a10 = __builtin_amdgcn_mfma_f32_16x16x32_bf16(qb, ma, a10, 0, 0, 0);
        a11 = __builtin_amdgcn_mfma_f32_16x16x32_bf16(qb, mb, a11, 0, 0, 0);
    }
    // C/D layout: col = lane&15, row = quad*4 + r  [HW-verified]
    int col = col_base + wj * 32 + m16;
    #pragma unroll
    for (int r = 0; r < 4; ++r) {
        int r0o = row_base + wi * 32 + quad * 4 + r;
        int r1o = r0o + 16;
        out[r0o * NB + col]      = fabsf(a00[r]);
        out[r0o * NB + col + 16] = fabsf(a01[r]);
        out[r1o * NB + col]      = fabsf(a10[r]);
        out[r1o * NB + col + 16] = fabsf(a11[r]);
    }
}

extern "C" void kernel_launch(void* const* d_in, const int* in_sizes, int n_in,
                              void* d_out, int out_size, void* d_ws, size_t ws_size,
                              hipStream_t stream) {
    const float* a = (const float*)d_in[0];       // 1024 x 4
    const float* b = (const float*)d_in[1];       // 1024 x 4
    const float* params = (const float*)d_in[2];  // 2 x 4 x 3
    float* out = (float*)d_out;                   // 1024 x 1024

    // >64 KB dynamic LDS: set the cap every call (idempotent, host-side, capture-safe).
    (void)hipFuncSetAttribute((const void*)qkm_fused,
                              hipFuncAttributeMaxDynamicSharedMemorySize, LDS_BYTES);
    qkm_fused<<<256, 256, LDS_BYTES, stream>>>(a, b, params, out);
}